// Round 5
// baseline (130.268 us; speedup 1.0000x reference)
//
#include <hip/hip_runtime.h>
#include <stdint.h>

// ComplexWaveformSystem: sim[b,t] = |rx[b,:] . conj(ifft_ortho(freq[t,:]))|^2 / temp
// B = 8192, T = 8192, L = 128, K = 2L = 256 (re/im interleaved bf16)

#define T_TOKENS 8192
#define B_BATCH  8192
#define L_SEQ    128

// GEMM geometry: BM=256 x BN=128, K chunks of 32 elems (64 B), ring-4 LDS slots
#define SLOT_BYTES 24576   // A region 16 KB + B region 8 KB
#define SB_OFF     16384

typedef __bf16 bf16x8 __attribute__((ext_vector_type(8)));
typedef float  f32x4  __attribute__((ext_vector_type(4)));
typedef unsigned int u32x4 __attribute__((ext_vector_type(4)));

__device__ __forceinline__ unsigned short f2bf(float f) {
  unsigned int u = __builtin_bit_cast(unsigned int, f);
  u += 0x7FFFu + ((u >> 16) & 1u);
  return (unsigned short)(u >> 16);
}

// ---------------- prep 1: bank = ifft_ortho(freq); interleaved bf16 (re,im) per u32
__global__ void build_bank_kernel(const float* __restrict__ fr,
                                  const float* __restrict__ fi,
                                  unsigned int* __restrict__ B2) {
  __shared__ float  sfr[L_SEQ], sfi[L_SEQ];
  __shared__ float2 stw[L_SEQ];
  const int t = blockIdx.x, l = threadIdx.x;
  sfr[l] = fr[t * L_SEQ + l];
  sfi[l] = fi[t * L_SEQ + l];
  float sn, cs;
  __sincosf(6.283185307179586f * (float)l * (1.0f / 128.0f), &sn, &cs);
  stw[l] = make_float2(cs, sn);
  __syncthreads();
  float br = 0.f, bi = 0.f;
#pragma unroll 8
  for (int k = 0; k < L_SEQ; ++k) {
    const float2 tw = stw[(k * l) & 127];
    const float xr = sfr[k], xi = sfi[k];
    br = fmaf(xr, tw.x, br); br = fmaf(-xi, tw.y, br);
    bi = fmaf(xr, tw.y, bi); bi = fmaf(xi, tw.x, bi);
  }
  const float sc = 0.08838834764831845f;  // 1/sqrt(128)
  const unsigned int lo = f2bf(br * sc);
  const unsigned int hi = f2bf(bi * sc);
  B2[t * L_SEQ + l] = lo | (hi << 16);
}

// ---------------- prep 2: A2[b][2l] = rx_r, A2[b][2l+1] = rx_i
__global__ void build_a_kernel(const float* __restrict__ rr,
                               const float* __restrict__ ri,
                               unsigned int* __restrict__ A2) {
  const int i = blockIdx.x * 256 + threadIdx.x;
  const unsigned int lo = f2bf(rr[i]);
  const unsigned int hi = f2bf(ri[i]);
  A2[i] = lo | (hi << 16);
}

// ---------------- GEMM, 8-phase counted-vmcnt schedule
// NOTE (r4->r5 NaN fix): NEVER pass a nonzero `offset` to global_load_lds —
// for the LDS-DMA path the instruction offset can contribute to the LDS write
// address (M0 + inst_offset), smearing chunks across slots. Chunk advance goes
// through the (laundered) global pointer instead, offset stays 0 — the exact
// pattern the proven r1 kernel used.
__device__ __forceinline__ void gl_lds16(const char* g, char* l) {
  __builtin_amdgcn_global_load_lds(
      (const __attribute__((address_space(1))) unsigned int*)g,
      (__attribute__((address_space(3))) unsigned int*)l, 16, 0, 0);
}

// imag A-fragment: per u32 word (re,im) -> (im,-re)
__device__ __forceinline__ bf16x8 make_imag(bf16x8 a) {
  u32x4 u = __builtin_bit_cast(u32x4, a);
#pragma unroll
  for (int i = 0; i < 4; ++i)
    u[i] = ((u[i] >> 16) | (u[i] << 16)) ^ 0x80000000u;
  return __builtin_bit_cast(bf16x8, u);
}

// bank-conflict swizzle: XOR byte bits [5:4] with s(row) = (row + row>>2) & 3
__device__ __forceinline__ int swz4(int row) { return ((row + (row >> 2)) & 3) << 4; }

extern __shared__ __align__(16) char smem[];   // 4 slots x 24 KB = 96 KB

__global__ __launch_bounds__(512, 1) void gemm_kernel(
    const char* __restrict__ A2, const char* __restrict__ B2,
    const float* __restrict__ temp, float* __restrict__ out) {
  const int tid  = threadIdx.x;
  const int lane = tid & 63;
  const int wid  = tid >> 6;

  // pin the temperature load BEFORE any staging so the vmcnt queue starts empty
  const float inv_t = 1.0f / temp[0];
  asm volatile("" :: "v"(inv_t));

  // XCD-bijective block swizzle: 2048 blocks, 256 contiguous per XCD
  const int bid  = blockIdx.x;
  const int swz  = (bid & 7) * 256 + (bid >> 3);
  const int brow = swz >> 6;   // 0..31  (batch / 256)
  const int bcol = swz & 63;   // 0..63  (tokens / 128)
  const int wr = wid >> 1, wc = wid & 1;   // 4M x 2N waves, 64x64 each

  // per-lane pre-swizzled global source pointers (chunk 0; chunk k adds k*64)
  const int l4 = lane >> 2, lm = lane & 3;
  const int rowA0 = wid * 32 + l4;
  const int rowA1 = rowA0 + 16;
  const int rowB  = wid * 16 + l4;
  const char* gA0 = A2 + (size_t)(brow * 256 + rowA0) * 512 + ((lm * 16) ^ swz4(rowA0));
  const char* gA1 = A2 + (size_t)(brow * 256 + rowA1) * 512 + ((lm * 16) ^ swz4(rowA1));
  const char* gB  = B2 + (size_t)(bcol * 128 + rowB ) * 512 + ((lm * 16) ^ swz4(rowB));

  // ds_read fragment offsets (region-relative, swizzled)
  int offA[4], offB[4];
  const int cb = (lane >> 4) * 16;
#pragma unroll
  for (int m = 0; m < 4; ++m) {
    const int r = wr * 64 + m * 16 + (lane & 15);
    offA[m] = r * 64 + (cb ^ swz4(r));
  }
#pragma unroll
  for (int n = 0; n < 4; ++n) {
    const int r = wc * 64 + n * 16 + (lane & 15);
    offB[n] = SB_OFF + r * 64 + (cb ^ swz4(r));
  }

  f32x4 accre[4][4], accim[4][4];
#pragma unroll
  for (int m = 0; m < 4; ++m)
#pragma unroll
    for (int n = 0; n < 4; ++n) {
      accre[m][n] = f32x4{0.f, 0.f, 0.f, 0.f};
      accim[m][n] = f32x4{0.f, 0.f, 0.f, 0.f};
    }

  // chunk offset laundered through an opaque VGPR so the compiler CANNOT fold
  // it back into the instruction's offset: immediate (must stay offset:0).
#define STAGE(KC) do {                                                     \
    char* sl_ = smem + ((KC) & 3) * SLOT_BYTES;                            \
    int koff_ = (KC) * 64;                                                 \
    asm("" : "+v"(koff_));                                                 \
    gl_lds16(gA0 + koff_, sl_ + wid * 2048);                               \
    gl_lds16(gA1 + koff_, sl_ + wid * 2048 + 1024);                        \
    gl_lds16(gB  + koff_, sl_ + SB_OFF + wid * 1024);                      \
  } while (0)

#define FENCE asm volatile("" ::: "memory")

// phase C: ds_read chunk C (slot C&3); stage chunk C+3; counted vmcnt retires chunk C+1.
// lgkmcnt(0) after barrier #1 pins this phase's ds_read completion before
// barrier #2 (WAR guard: next phase's STAGE overwrites slot (C-1)&3).
#define PHASE(C, VM, DOSTAGE) do {                                         \
    const char* slb_ = smem + ((C) & 3) * SLOT_BYTES;                      \
    bf16x8 a_[4], b_[4];                                                   \
    _Pragma("unroll") for (int m = 0; m < 4; ++m)                          \
      a_[m] = *(const bf16x8*)(slb_ + offA[m]);                            \
    _Pragma("unroll") for (int n = 0; n < 4; ++n)                          \
      b_[n] = *(const bf16x8*)(slb_ + offB[n]);                            \
    if (DOSTAGE) { STAGE((C) + 3); }                                       \
    if ((VM) == 4)      asm volatile("s_waitcnt vmcnt(4)" ::: "memory");   \
    else if ((VM) == 3) asm volatile("s_waitcnt vmcnt(3)" ::: "memory");   \
    else if ((VM) == 0) asm volatile("s_waitcnt vmcnt(0)" ::: "memory");   \
    __builtin_amdgcn_s_barrier();                                          \
    asm volatile("s_waitcnt lgkmcnt(0)" ::: "memory");                     \
    __builtin_amdgcn_s_setprio(1);                                         \
    _Pragma("unroll") for (int m = 0; m < 4; ++m) {                        \
      const bf16x8 ai_ = make_imag(a_[m]);                                 \
      _Pragma("unroll") for (int n = 0; n < 4; ++n) {                      \
        accre[m][n] = __builtin_amdgcn_mfma_f32_16x16x32_bf16(             \
            a_[m], b_[n], accre[m][n], 0, 0, 0);                           \
        accim[m][n] = __builtin_amdgcn_mfma_f32_16x16x32_bf16(             \
            ai_, b_[n], accim[m][n], 0, 0, 0);                             \
      }                                                                    \
    }                                                                      \
    __builtin_amdgcn_s_setprio(0);                                         \
    __builtin_amdgcn_s_barrier();                                          \
    FENCE;                                                                 \
  } while (0)

  // queue provably empty before staging begins
  asm volatile("s_waitcnt vmcnt(0) lgkmcnt(0)" ::: "memory");

  // prologue: stage chunks 0,1,2 (9 loads); retire chunk 0 (+ margin)
  STAGE(0); STAGE(1); STAGE(2);
  asm volatile("s_waitcnt vmcnt(4)" ::: "memory");
  __builtin_amdgcn_s_barrier();
  FENCE;

  PHASE(0, 4, 1);
  PHASE(1, 4, 1);
  PHASE(2, 4, 1);
  PHASE(3, 4, 1);
  PHASE(4, 4, 1);
  PHASE(5, 3, 0);
  PHASE(6, 0, 0);
  PHASE(7, -1, 0);

#undef PHASE
#undef STAGE

  // epilogue: sim = (re^2 + im^2) * inv_t ; C layout col=lane&15, row=(lane>>4)*4+reg
  const int r0 = brow * 256 + wr * 64 + ((lane >> 4) << 2);
  const int c0 = bcol * 128 + wc * 64 + (lane & 15);
#pragma unroll
  for (int m = 0; m < 4; ++m) {
#pragma unroll
    for (int n = 0; n < 4; ++n) {
      const f32x4 re = accre[m][n];
      const f32x4 im = accim[m][n];
#pragma unroll
      for (int j = 0; j < 4; ++j) {
        out[(size_t)(r0 + m * 16 + j) * T_TOKENS + (c0 + n * 16)] =
            (re[j] * re[j] + im[j] * im[j]) * inv_t;
      }
    }
  }
}

extern "C" void kernel_launch(void* const* d_in, const int* in_sizes, int n_in,
                              void* d_out, int out_size, void* d_ws, size_t ws_size,
                              hipStream_t stream) {
  const float* rx_r = (const float*)d_in[0];
  const float* rx_i = (const float*)d_in[1];
  const float* fq_r = (const float*)d_in[2];
  const float* fq_i = (const float*)d_in[3];
  const float* temp = (const float*)d_in[4];
  float* out = (float*)d_out;

  unsigned int* B2 = (unsigned int*)d_ws;                          // 4 MB bank
  unsigned int* A2 = (unsigned int*)((char*)d_ws + (4u << 20));    // 4 MB rx

  (void)hipFuncSetAttribute((const void*)gemm_kernel,
                            hipFuncAttributeMaxDynamicSharedMemorySize, 98304);

  build_bank_kernel<<<T_TOKENS, L_SEQ, 0, stream>>>(fq_r, fq_i, B2);
  build_a_kernel<<<(B_BATCH * L_SEQ) / 256, 256, 0, stream>>>(rx_r, rx_i, A2);
  gemm_kernel<<<(B_BATCH / 256) * (T_TOKENS / 128), 512, 98304, stream>>>(
      (const char*)A2, (const char*)B2, temp, out);
}